// Round 13
// baseline (290.030 us; speedup 1.0000x reference)
//
#include <hip/hip_runtime.h>
#include <hip/hip_cooperative_groups.h>
#include <math.h>

namespace cg = cooperative_groups;

#define N_NODES 8192
#define N_EDGES 262144
#define NFEAT 128
#define NHID 256
#define NCLASS 16
#define ELLS 96   // ELL stride; P(Poisson(32) >= 96) ~ 1e-18 per row

// f32 -> bf16 with round-to-nearest-even
__device__ inline unsigned int f2bf(float f) {
    unsigned int u = __float_as_uint(f);
    u += 0x7fffu + ((u >> 16) & 1u);
    return u >> 16;
}

#define CVT4(v, f) { \
    f[0] = __uint_as_float((v).x << 16); f[1] = __uint_as_float((v).x & 0xffff0000u); \
    f[2] = __uint_as_float((v).y << 16); f[3] = __uint_as_float((v).y & 0xffff0000u); }

// ================= cooperative mega-kernel: grid 512 x 256 (2 blocks/CU) =================
// S0 zero cnt | S1 edges->ELL (2 passes) | S2 deg/dinv/xs (2 passes) |
// S3 gather->AX->H->V2s (2 passes) | S4 gather->log_softmax (2 passes)
__global__ __launch_bounds__(256) void mega_kernel(const int* __restrict__ ei,
                                                   const float* __restrict__ ew,
                                                   const float* __restrict__ x,
                                                   const float* __restrict__ W1,
                                                   const float* __restrict__ b1,
                                                   const float* __restrict__ W2,
                                                   const float* __restrict__ b2,
                                                   int* __restrict__ cnt,
                                                   float* __restrict__ dinv,
                                                   int2* __restrict__ ell,
                                                   float* __restrict__ V2s,
                                                   uint2* __restrict__ xs2,
                                                   float* __restrict__ out) {
    cg::grid_group grid = cg::this_grid();
    __shared__ float axs[8][NFEAT];        // 4 KB
    __shared__ float hs[8][NHID + 4];      // 8.125 KB
    __shared__ float part[256];            // 1 KB
    int t = threadIdx.x;
    int b = blockIdx.x;

    // ---- S0: zero cnt (8192 words) ----
    if (b < 32) cnt[b * 256 + t] = 0;
    grid.sync();

    // ---- S1: one pass over edges: count + ELL store (raw weight) ----
    #pragma unroll
    for (int pass = 0; pass < 2; ++pass) {
        int e = (b + pass * 512) * 256 + t;       // covers [0, E) exactly
        int r1 = ei[e];
        int c1 = ei[N_EDGES + e];
        float w1 = ew[e];
        int slot = atomicAdd(&cnt[r1], 1);
        ell[r1 * ELLS + slot] = make_int2(c1, __float_as_int(w1));
    }
    grid.sync();

    // ---- S2: per row deg/dinv + xs = bf16(dinv * x). Same (r,lane) mapping as S3A:
    //      per-pass n, di, self-word kept in registers across the sync. ----
    int lane = t & 31;
    int rloc = t >> 5;
    int nA[2]; float diA[2]; uint2 oA[2];
    #pragma unroll
    for (int pass = 0; pass < 2; ++pass) {
        int r = (b + pass * 512) * 8 + rloc;
        int n = cnt[r];
        float sum = 0.0f;
        for (int base = 0; base < n; base += 32) {
            int idx = base + lane;
            if (idx < n) sum += __int_as_float(ell[r * ELLS + idx].y);
        }
        #pragma unroll
        for (int off = 1; off < 32; off <<= 1) sum += __shfl_xor(sum, off, 32);
        float di = rsqrtf(sum + 1.0f);            // + self loop, always >= 1
        if (lane == 0) dinv[r] = di;
        const float4* xp = (const float4*)(x + (size_t)r * NFEAT + lane * 4);
        float4 a = xp[0];
        uint2 o;
        o.x = f2bf(di * a.x) | (f2bf(di * a.y) << 16);
        o.y = f2bf(di * a.z) | (f2bf(di * a.w) << 16);
        xs2[r * 32 + lane] = o;
        nA[pass] = n; diA[pass] = di; oA[pass] = o;
    }
    grid.sync();

    // ---- S3: per pass: phase A gather -> B (AX@W1,relu) -> C (H@W2, scale) ----
    #pragma unroll
    for (int pass = 0; pass < 2; ++pass) {
        int bb8 = (b + pass * 512) * 8;
        int r = bb8 + rloc;
        int n = nA[pass];
        {   // phase A
            float acc[4];
            CVT4(oA[pass], acc);                  // self term (already dinv-scaled)
            for (int base = 0; base < n; base += 8) {
                int2 cw = ell[r * ELLS + base + (lane & 7)];
                #pragma unroll
                for (int u = 0; u < 8; ++u) {
                    int k = base + u;
                    int c = __shfl(cw.x, u, 8) & (N_NODES - 1);   // clamp garbage tails
                    float w = __int_as_float(__shfl(cw.y, u, 8));
                    w = (k < n) ? w : 0.0f;                       // mask tail
                    uint2 v = xs2[c * 32 + lane];
                    float vf[4]; CVT4(v, vf);
                    #pragma unroll
                    for (int i = 0; i < 4; ++i) acc[i] += w * vf[i];
                }
            }
            float di = diA[pass];
            #pragma unroll
            for (int i = 0; i < 4; ++i) acc[i] *= di;
            ((float4*)&axs[rloc][lane * 4])[0] = make_float4(acc[0], acc[1], acc[2], acc[3]);
        }
        __syncthreads();
        {   // phase B
            float hacc[8];
            #pragma unroll
            for (int q = 0; q < 8; ++q) hacc[q] = 0.0f;
            #pragma unroll 4
            for (int k = 0; k < NFEAT; ++k) {
                float w = W1[k * NHID + t];
                #pragma unroll
                for (int q = 0; q < 8; ++q) hacc[q] += axs[q][k] * w;
            }
            float bv = b1[t];
            #pragma unroll
            for (int q = 0; q < 8; ++q) {
                float v = hacc[q] + bv;
                hs[q][t] = v > 0.0f ? v : 0.0f;
            }
        }
        __syncthreads();
        {   // phase C
            int j = t & 15;
            int rq = (t >> 4) & 7;
            int kb = (t >> 7) * 128;
            float p = 0.0f;
            #pragma unroll 8
            for (int k = 0; k < 128; ++k) p += hs[rq][kb + k] * W2[(kb + k) * NCLASS + j];
            part[t] = p;
            __syncthreads();
            if (t < 128) {
                int rg = bb8 + (t >> 4);
                V2s[rg * NCLASS + (t & 15)] = dinv[rg] * (part[t] + part[t + 128]);
            }
        }
        __syncthreads();
    }
    grid.sync();

    // ---- S4: out[r] = log_softmax(di*(V2s[r] + sum w*V2s[c]) + b2) ----
    if (t < 128) {
        #pragma unroll
        for (int pass = 0; pass < 2; ++pass) {
            int j = t & 15;
            int r4 = (b + pass * 512) * 8 + (t >> 4);
            int n4 = cnt[r4];
            float di4 = dinv[r4];
            float acc4 = V2s[r4 * NCLASS + j];    // self term (already dinv-scaled)
            for (int base = 0; base < n4; base += 8) {
                int2 cw = ell[r4 * ELLS + base + (j & 7)];
                #pragma unroll
                for (int u = 0; u < 8; ++u) {
                    int k = base + u;
                    int c = __shfl(cw.x, u, 8) & (N_NODES - 1);
                    float w = __int_as_float(__shfl(cw.y, u, 8));
                    w = (k < n4) ? w : 0.0f;
                    acc4 += w * V2s[c * NCLASS + j];
                }
            }
            float v = di4 * acc4 + b2[j];
            float mx = v;
            #pragma unroll
            for (int off = 1; off < 16; off <<= 1) mx = fmaxf(mx, __shfl_xor(mx, off));
            float ex = expf(v - mx);
            float ssum = ex;
            #pragma unroll
            for (int off = 1; off < 16; off <<= 1) ssum += __shfl_xor(ssum, off);
            out[r4 * NCLASS + j] = v - mx - logf(ssum);
        }
    }
}

// ================= fallback path: round-11's proven 5 kernels =================
__global__ void zero_kernel(int* __restrict__ p) {
    p[blockIdx.x * 256 + threadIdx.x] = 0;
}

__global__ __launch_bounds__(256) void histscatter_kernel(const int* __restrict__ ei,
                                                          const float* __restrict__ ew,
                                                          int* __restrict__ cnt,
                                                          int2* __restrict__ ell) {
    int e = blockIdx.x * 256 + threadIdx.x;
    int r = ei[e];
    int c = ei[N_EDGES + e];
    float w = ew[e];
    int slot = atomicAdd(&cnt[r], 1);
    ell[r * ELLS + slot] = make_int2(c, __float_as_int(w));
}

__global__ __launch_bounds__(256) void dinvcvt_kernel(const int* __restrict__ cnt,
                                                      const int2* __restrict__ ell,
                                                      const float* __restrict__ x,
                                                      float* __restrict__ dinv,
                                                      uint4* __restrict__ xs) {
    int t = threadIdx.x;
    int j = t & 15;
    int r = blockIdx.x * 16 + (t >> 4);
    int n = cnt[r];
    float sum = 0.0f;
    for (int base = 0; base < n; base += 16) {
        int idx = base + j;
        if (idx < n) sum += __int_as_float(ell[r * ELLS + idx].y);
    }
    #pragma unroll
    for (int off = 1; off < 16; off <<= 1) sum += __shfl_xor(sum, off, 16);
    float di = rsqrtf(sum + 1.0f);
    if (j == 0) dinv[r] = di;
    const float4* xp = (const float4*)(x + (size_t)r * NFEAT + j * 8);
    float4 a = xp[0], c4 = xp[1];
    uint4 o;
    o.x = f2bf(di * a.x) | (f2bf(di * a.y) << 16);
    o.y = f2bf(di * a.z) | (f2bf(di * a.w) << 16);
    o.z = f2bf(di * c4.x) | (f2bf(di * c4.y) << 16);
    o.w = f2bf(di * c4.z) | (f2bf(di * c4.w) << 16);
    xs[r * 16 + j] = o;
}

__global__ __launch_bounds__(256) void layer12_kernel(const int* __restrict__ cnt,
                                                      const int2* __restrict__ ell,
                                                      const uint2* __restrict__ xs2,
                                                      const float* __restrict__ dinv,
                                                      const float* __restrict__ W1,
                                                      const float* __restrict__ b1,
                                                      const float* __restrict__ W2,
                                                      float* __restrict__ V2s) {
    __shared__ float axs[8][NFEAT];
    __shared__ float hs[8][NHID + 4];
    __shared__ float part[256];
    int t = threadIdx.x;
    int lane = t & 31;
    int rloc = t >> 5;
    int r = blockIdx.x * 8 + rloc;
    int n = cnt[r];
    float di = dinv[r];
    uint2 xv = xs2[r * 32 + lane];
    float acc[4];
    CVT4(xv, acc);
    for (int base = 0; base < n; base += 8) {
        int2 cw = ell[r * ELLS + base + (lane & 7)];
        #pragma unroll
        for (int u = 0; u < 8; ++u) {
            int k = base + u;
            int c = __shfl(cw.x, u, 8) & (N_NODES - 1);
            float w = __int_as_float(__shfl(cw.y, u, 8));
            w = (k < n) ? w : 0.0f;
            uint2 v = xs2[c * 32 + lane];
            float vf[4]; CVT4(v, vf);
            #pragma unroll
            for (int i = 0; i < 4; ++i) acc[i] += w * vf[i];
        }
    }
    #pragma unroll
    for (int i = 0; i < 4; ++i) acc[i] *= di;
    ((float4*)&axs[rloc][lane * 4])[0] = make_float4(acc[0], acc[1], acc[2], acc[3]);
    __syncthreads();
    float hacc[8];
    #pragma unroll
    for (int q = 0; q < 8; ++q) hacc[q] = 0.0f;
    #pragma unroll 4
    for (int k = 0; k < NFEAT; ++k) {
        float w = W1[k * NHID + t];
        #pragma unroll
        for (int q = 0; q < 8; ++q) hacc[q] += axs[q][k] * w;
    }
    float bb = b1[t];
    #pragma unroll
    for (int q = 0; q < 8; ++q) {
        float v = hacc[q] + bb;
        hs[q][t] = v > 0.0f ? v : 0.0f;
    }
    __syncthreads();
    int j = t & 15;
    int rq = (t >> 4) & 7;
    int kb = (t >> 7) * 128;
    float p = 0.0f;
    #pragma unroll 8
    for (int k = 0; k < 128; ++k) p += hs[rq][kb + k] * W2[(kb + k) * NCLASS + j];
    part[t] = p;
    __syncthreads();
    if (t < 128) {
        int rg = blockIdx.x * 8 + (t >> 4);
        V2s[rg * NCLASS + (t & 15)] = dinv[rg] * (part[t] + part[t + 128]);
    }
}

__global__ __launch_bounds__(256) void agg2_kernel(const int* __restrict__ cnt,
                                                   const int2* __restrict__ ell,
                                                   const float* __restrict__ V2s,
                                                   const float* __restrict__ dinv,
                                                   const float* __restrict__ b2,
                                                   float* __restrict__ out) {
    int t = threadIdx.x;
    int j = t & 15;
    int r = blockIdx.x * 16 + (t >> 4);
    int n = cnt[r];
    float di = dinv[r];
    float acc = V2s[r * NCLASS + j];
    for (int base = 0; base < n; base += 8) {
        int2 cw = ell[r * ELLS + base + (j & 7)];
        #pragma unroll
        for (int u = 0; u < 8; ++u) {
            int k = base + u;
            int c = __shfl(cw.x, u, 8) & (N_NODES - 1);
            float w = __int_as_float(__shfl(cw.y, u, 8));
            w = (k < n) ? w : 0.0f;
            acc += w * V2s[c * NCLASS + j];
        }
    }
    float v = di * acc + b2[j];
    float mx = v;
    #pragma unroll
    for (int off = 1; off < 16; off <<= 1) mx = fmaxf(mx, __shfl_xor(mx, off));
    float ex = expf(v - mx);
    float ssum = ex;
    #pragma unroll
    for (int off = 1; off < 16; off <<= 1) ssum += __shfl_xor(ssum, off);
    out[r * NCLASS + j] = v - mx - logf(ssum);
}

extern "C" void kernel_launch(void* const* d_in, const int* in_sizes, int n_in,
                              void* d_out, int out_size, void* d_ws, size_t ws_size,
                              hipStream_t stream) {
    const float* x  = (const float*)d_in[0];
    const int*   ei = (const int*)d_in[1];      // [2, E] flat: row = ei[e], col = ei[E+e]
    const float* ew = (const float*)d_in[2];
    const float* W1 = (const float*)d_in[3];
    const float* b1 = (const float*)d_in[4];
    const float* W2 = (const float*)d_in[5];
    const float* b2 = (const float*)d_in[6];
    float* out = (float*)d_out;

    char* ws = (char*)d_ws;
    int*   cnt  = (int*)  (ws);                  // [0, 32K)
    float* dinv = (float*)(ws + 32768);          // [32K, 64K)
    int2*  ell  = (int2*) (ws + 65536);          // [64K, 64K+6M): 8192*96*8 B
    float* V2s  = (float*)(ws + 8388608);        // [8M, 8.5M)
    uint2* xs2  = (uint2*)(ws + 16777216);       // [16M, 18M): bf16 dinv-scaled x

    void* args[] = {(void*)&ei, (void*)&ew, (void*)&x, (void*)&W1, (void*)&b1,
                    (void*)&W2, (void*)&b2, (void*)&cnt, (void*)&dinv, (void*)&ell,
                    (void*)&V2s, (void*)&xs2, (void*)&out};
    hipError_t st = hipLaunchCooperativeKernel((const void*)mega_kernel, dim3(512),
                                               dim3(256), args, 0, stream);
    if (st != hipSuccess) {
        // deterministic fallback: proven round-11 5-kernel path
        zero_kernel<<<32, 256, 0, stream>>>(cnt);
        histscatter_kernel<<<N_EDGES / 256, 256, 0, stream>>>(ei, ew, cnt, ell);
        dinvcvt_kernel<<<N_NODES / 16, 256, 0, stream>>>(cnt, ell, x, dinv, (uint4*)xs2);
        layer12_kernel<<<N_NODES / 8, 256, 0, stream>>>(cnt, ell, xs2, dinv, W1, b1, W2, V2s);
        agg2_kernel<<<N_NODES / 16, 256, 0, stream>>>(cnt, ell, V2s, dinv, b2, out);
    }
}

// Round 15
// 69.217 us; speedup vs baseline: 4.1902x; 4.1902x over previous
//
#include <hip/hip_runtime.h>
#include <math.h>

#define N_NODES 8192
#define N_EDGES 262144
#define NFEAT 128
#define NHID 256
#define NCLASS 16
#define ELLS 96   // ELL stride; P(Poisson(32) >= 96) ~ 1e-18 per row

// LESSON (round 13): grid.sync() cooperative mega-kernel = ~58 us PER SYNC on
// MI355X at 512 blocks (278 us total vs 59.7 for separate kernels). Never again.
// LESSON (round 14): V2s is dinv-pre-scaled; folding di[c] into agg2's edge
// weight double-counts it. Layer-2 gather must use RAW weights.

// ---------------- zero deg + cnt (contiguous 64 KB) ----------------
__global__ void zero_kernel(int* __restrict__ p) {
    p[blockIdx.x * 256 + threadIdx.x] = 0;   // 64 blocks x 256 = 16384 words
}

// ---------------- one pass over edges: deg + count + ELL store (raw weight) ----------------
__global__ __launch_bounds__(256) void histscatter_kernel(const int* __restrict__ ei,
                                                          const float* __restrict__ ew,
                                                          float* __restrict__ deg,
                                                          int* __restrict__ cnt,
                                                          int2* __restrict__ ell) {
    int e = blockIdx.x * 256 + threadIdx.x;     // 1024 blocks == E exactly
    int r = ei[e];
    int c = ei[N_EDGES + e];
    float w = ew[e];
    atomicAdd(&deg[r], w);
    int slot = atomicAdd(&cnt[r], 1);
    ell[r * ELLS + slot] = make_int2(c, __float_as_int(w));
}

// ---------------- fused: ELL gather on f32 x -> AX -> H=relu(AX@W1+b1) -> V2s=di*(H@W2) ----------------
// 8 rows/block, 1024 blocks, 32 lanes/row, float4/lane. LDS ~13.2 KB.
// Layer-1 gather: x is RAW, so staging lane folds di[c] into the weight before
// the shfl broadcast (inner 8-unroll stays shfl+shfl+load+4FMA).
__global__ __launch_bounds__(256) void layer12_kernel(const float* __restrict__ deg,
                                                      const int* __restrict__ cnt,
                                                      const int2* __restrict__ ell,
                                                      const float* __restrict__ x,
                                                      const float* __restrict__ W1,
                                                      const float* __restrict__ b1,
                                                      const float* __restrict__ W2,
                                                      float* __restrict__ V2s) {
    __shared__ float axs[8][NFEAT];        // 4 KB
    __shared__ float hs[8][NHID + 4];      // 8.125 KB
    __shared__ float part[256];            // 1 KB
    int t = threadIdx.x;

    // ---- phase A: acc = di*x[r] + sum w_eff*x[c]; AX = di*acc
    int lane = t & 31;
    int rloc = t >> 5;
    int r = blockIdx.x * 8 + rloc;
    int n = cnt[r];
    float di = rsqrtf(deg[r] + 1.0f);       // + self loop, always >= 1
    const float4* x4 = (const float4*)x;
    float4 xv = x4[r * 32 + lane];
    float acc[4] = {di * xv.x, di * xv.y, di * xv.z, di * xv.w};
    for (int base = 0; base < n; base += 8) {
        int idx = base + (lane & 7);
        int2 cw = ell[r * ELLS + idx];
        int cc = cw.x & (N_NODES - 1);                       // clamp garbage tail
        float wl = __int_as_float(cw.y) * rsqrtf(deg[cc] + 1.0f);
        wl = (idx < n) ? wl : 0.0f;                          // mask tail
        #pragma unroll
        for (int u = 0; u < 8; ++u) {
            int c = __shfl(cc, u, 8);
            float w = __shfl(wl, u, 8);
            float4 v = x4[c * 32 + lane];
            acc[0] += w * v.x; acc[1] += w * v.y; acc[2] += w * v.z; acc[3] += w * v.w;
        }
    }
    #pragma unroll
    for (int i = 0; i < 4; ++i) acc[i] *= di;
    ((float4*)&axs[rloc][lane * 4])[0] = make_float4(acc[0], acc[1], acc[2], acc[3]);
    __syncthreads();

    // ---- phase B: hs[q][t] = relu(sum_k axs[q][k] * W1[k][t] + b1[t]); t = column
    float hacc[8];
    #pragma unroll
    for (int q = 0; q < 8; ++q) hacc[q] = 0.0f;
    #pragma unroll 4
    for (int k = 0; k < NFEAT; ++k) {
        float w = W1[k * NHID + t];
        #pragma unroll
        for (int q = 0; q < 8; ++q) hacc[q] += axs[q][k] * w;
    }
    float bb = b1[t];
    #pragma unroll
    for (int q = 0; q < 8; ++q) {
        float v = hacc[q] + bb;
        hs[q][t] = v > 0.0f ? v : 0.0f;
    }
    __syncthreads();

    // ---- phase C: V2s[r][j] = rsqrt(deg[r]+1) * sum_k hs[r][k] * W2[k][j]
    int j = t & 15;
    int rq = (t >> 4) & 7;
    int kb = (t >> 7) * 128;
    float p = 0.0f;
    #pragma unroll 8
    for (int k = 0; k < 128; ++k) p += hs[rq][kb + k] * W2[(kb + k) * NCLASS + j];
    part[t] = p;
    __syncthreads();
    if (t < 128) {
        int rg = blockIdx.x * 8 + (t >> 4);
        float dig = rsqrtf(deg[rg] + 1.0f);
        V2s[rg * NCLASS + (t & 15)] = dig * (part[t] + part[t + 128]);
    }
}

// ---------------- out[r] = log_softmax(di*(V2s[r] + sum w_raw*V2s[c]) + b2) ----------------
// V2s already carries di[c]; weights here are RAW (round-14 lesson).
__global__ __launch_bounds__(256) void agg2_kernel(const float* __restrict__ deg,
                                                   const int* __restrict__ cnt,
                                                   const int2* __restrict__ ell,
                                                   const float* __restrict__ V2s,
                                                   const float* __restrict__ b2,
                                                   float* __restrict__ out) {
    int t = threadIdx.x;
    int j = t & 15;                   // class
    int r = blockIdx.x * 16 + (t >> 4);
    int n = cnt[r];
    float di = rsqrtf(deg[r] + 1.0f);
    float acc = V2s[r * NCLASS + j];  // self term (V2s already dinv-scaled)
    for (int base = 0; base < n; base += 8) {
        int idx = base + (j & 7);
        int2 cw = ell[r * ELLS + idx];
        int cc = cw.x & (N_NODES - 1);
        float wl = __int_as_float(cw.y);
        wl = (idx < n) ? wl : 0.0f;
        #pragma unroll
        for (int u = 0; u < 8; ++u) {
            int c = __shfl(cc, u, 8);
            float w = __shfl(wl, u, 8);
            acc += w * V2s[c * NCLASS + j];
        }
    }
    float v = di * acc + b2[j];
    // log_softmax across the 16 lanes of this row-group
    float mx = v;
    #pragma unroll
    for (int off = 1; off < 16; off <<= 1) mx = fmaxf(mx, __shfl_xor(mx, off));
    float ex = expf(v - mx);
    float ssum = ex;
    #pragma unroll
    for (int off = 1; off < 16; off <<= 1) ssum += __shfl_xor(ssum, off);
    out[r * NCLASS + j] = v - mx - logf(ssum);
}

extern "C" void kernel_launch(void* const* d_in, const int* in_sizes, int n_in,
                              void* d_out, int out_size, void* d_ws, size_t ws_size,
                              hipStream_t stream) {
    const float* x  = (const float*)d_in[0];
    const int*   ei = (const int*)d_in[1];      // [2, E] flat: row = ei[e], col = ei[E+e]
    const float* ew = (const float*)d_in[2];
    const float* W1 = (const float*)d_in[3];
    const float* b1 = (const float*)d_in[4];
    const float* W2 = (const float*)d_in[5];
    const float* b2 = (const float*)d_in[6];
    float* out = (float*)d_out;

    char* ws = (char*)d_ws;
    float* deg  = (float*)(ws);                  // [0, 32K)
    int*   cnt  = (int*)  (ws + 32768);          // [32K, 64K)
    int2*  ell  = (int2*) (ws + 65536);          // [64K, 64K+6M): 8192*96*8 B
    float* V2s  = (float*)(ws + 8388608);        // [8M, 8.5M)

    zero_kernel<<<64, 256, 0, stream>>>((int*)ws);   // deg + cnt

    histscatter_kernel<<<N_EDGES / 256, 256, 0, stream>>>(ei, ew, deg, cnt, ell);

    layer12_kernel<<<N_NODES / 8, 256, 0, stream>>>(deg, cnt, ell, x, W1, b1, W2, V2s);
    agg2_kernel<<<N_NODES / 16, 256, 0, stream>>>(deg, cnt, ell, V2s, b2, out);
}

// Round 16
// 59.333 us; speedup vs baseline: 4.8882x; 1.1666x over previous
//
#include <hip/hip_runtime.h>
#include <math.h>

#define N_NODES 8192
#define N_EDGES 262144
#define NFEAT 128
#define NHID 256
#define NCLASS 16
#define ELLS 96   // ELL stride; P(Poisson(32) >= 96) ~ 1e-18 per row

// LESSON (round 13): grid.sync() mega-kernel = ~58 us PER SYNC at 512 blocks. Never.
// LESSON (round 15): any dependent load (deg[c]) in the gather staging chain
// costs ~10 us across the two gathers. Keep normalization pre-folded: xs carries
// di[c] for layer 1, V2s carries di[c] for layer 2; staging = one ELL load only.

// f32 -> bf16 with round-to-nearest-even
__device__ inline unsigned int f2bf(float f) {
    unsigned int u = __float_as_uint(f);
    u += 0x7fffu + ((u >> 16) & 1u);
    return u >> 16;
}

#define CVT4(v, f) { \
    f[0] = __uint_as_float((v).x << 16); f[1] = __uint_as_float((v).x & 0xffff0000u); \
    f[2] = __uint_as_float((v).y << 16); f[3] = __uint_as_float((v).y & 0xffff0000u); }

// ---------------- zero cnt (32 KB) ----------------
__global__ void zero_kernel(int* __restrict__ p) {
    p[blockIdx.x * 256 + threadIdx.x] = 0;   // 32 blocks x 256 = 8192 words
}

// ---------------- one pass over edges: count + ELL store (raw weight) ----------------
__global__ __launch_bounds__(256) void histscatter_kernel(const int* __restrict__ ei,
                                                          const float* __restrict__ ew,
                                                          int* __restrict__ cnt,
                                                          int2* __restrict__ ell) {
    int e = blockIdx.x * 256 + threadIdx.x;     // 1024 blocks == E exactly
    int r = ei[e];
    int c = ei[N_EDGES + e];
    float w = ew[e];
    int slot = atomicAdd(&cnt[r], 1);
    ell[r * ELLS + slot] = make_int2(c, __float_as_int(w));
}

// ---------------- per row: deg = sum(ell w), dinv = rsqrt(deg+1), xs = bf16(dinv*x) ----------------
// 16 rows/block, 16 lanes/row. No atomics: reads the ELL row it owns.
__global__ __launch_bounds__(256) void dinvcvt_kernel(const int* __restrict__ cnt,
                                                      const int2* __restrict__ ell,
                                                      const float* __restrict__ x,
                                                      float* __restrict__ dinv,
                                                      uint4* __restrict__ xs) {
    int t = threadIdx.x;
    int j = t & 15;
    int r = blockIdx.x * 16 + (t >> 4);
    int n = cnt[r];
    float sum = 0.0f;
    for (int base = 0; base < n; base += 16) {
        int idx = base + j;
        if (idx < n) sum += __int_as_float(ell[r * ELLS + idx].y);
    }
    #pragma unroll
    for (int off = 1; off < 16; off <<= 1) sum += __shfl_xor(sum, off, 16);
    float di = rsqrtf(sum + 1.0f);              // + self loop, always >= 1
    if (j == 0) dinv[r] = di;
    const float4* xp = (const float4*)(x + (size_t)r * NFEAT + j * 8);
    float4 a = xp[0], b = xp[1];
    uint4 o;
    o.x = f2bf(di * a.x) | (f2bf(di * a.y) << 16);
    o.y = f2bf(di * a.z) | (f2bf(di * a.w) << 16);
    o.z = f2bf(di * b.x) | (f2bf(di * b.y) << 16);
    o.w = f2bf(di * b.z) | (f2bf(di * b.w) << 16);
    xs[r * 16 + j] = o;
}

// ---------------- fused: ELL gather on xs -> AX -> H=relu(AX@W1+b1) -> V2s=dinv*(H@W2) ----------------
// 8 rows/block, 1024 blocks, 32 lanes/row. LDS ~13.2 KB -> high occupancy.
// 16-wide staging chunks: one coalesced ELL load feeds 16 broadcast iterations.
__global__ __launch_bounds__(256) void layer12_kernel(const int* __restrict__ cnt,
                                                      const int2* __restrict__ ell,
                                                      const uint2* __restrict__ xs2,
                                                      const float* __restrict__ dinv,
                                                      const float* __restrict__ W1,
                                                      const float* __restrict__ b1,
                                                      const float* __restrict__ W2,
                                                      float* __restrict__ V2s) {
    __shared__ float axs[8][NFEAT];        // 4 KB
    __shared__ float hs[8][NHID + 4];      // 8.125 KB
    __shared__ float part[256];            // 1 KB
    int t = threadIdx.x;

    // ---- phase A: acc = xs[r] + sum w*xs[c]; AX = dinv[r]*acc
    int lane = t & 31;
    int rloc = t >> 5;
    int r = blockIdx.x * 8 + rloc;
    int n = cnt[r];
    float di = dinv[r];
    uint2 xv = xs2[r * 32 + lane];
    float acc[4];
    CVT4(xv, acc);                          // self term (xs already dinv-scaled)
    for (int base = 0; base < n; base += 16) {
        int idx = base + (lane & 15);
        int2 cw = ell[r * ELLS + idx];
        int cc = cw.x & (N_NODES - 1);                 // clamp garbage tail
        float wl = __int_as_float(cw.y);
        wl = (idx < n) ? wl : 0.0f;                    // mask folded pre-broadcast
        #pragma unroll
        for (int u = 0; u < 16; ++u) {
            int c = __shfl(cc, u, 16);
            float w = __shfl(wl, u, 16);
            uint2 v = xs2[c * 32 + lane];
            float vf[4]; CVT4(v, vf);
            #pragma unroll
            for (int i = 0; i < 4; ++i) acc[i] += w * vf[i];
        }
    }
    #pragma unroll
    for (int i = 0; i < 4; ++i) acc[i] *= di;
    ((float4*)&axs[rloc][lane * 4])[0] = make_float4(acc[0], acc[1], acc[2], acc[3]);
    __syncthreads();

    // ---- phase B: hs[q][t] = relu(sum_k axs[q][k] * W1[k][t] + b1[t]); t = column
    float hacc[8];
    #pragma unroll
    for (int q = 0; q < 8; ++q) hacc[q] = 0.0f;
    #pragma unroll 4
    for (int k = 0; k < NFEAT; ++k) {
        float w = W1[k * NHID + t];
        #pragma unroll
        for (int q = 0; q < 8; ++q) hacc[q] += axs[q][k] * w;
    }
    float bb = b1[t];
    #pragma unroll
    for (int q = 0; q < 8; ++q) {
        float v = hacc[q] + bb;
        hs[q][t] = v > 0.0f ? v : 0.0f;
    }
    __syncthreads();

    // ---- phase C: V2s[r][j] = dinv[r] * sum_k hs[r][k] * W2[k][j]; W2 via L1/L2
    int j = t & 15;
    int rq = (t >> 4) & 7;
    int kb = (t >> 7) * 128;
    float p = 0.0f;
    #pragma unroll 8
    for (int k = 0; k < 128; ++k) p += hs[rq][kb + k] * W2[(kb + k) * NCLASS + j];
    part[t] = p;
    __syncthreads();
    if (t < 128) {
        int rg = blockIdx.x * 8 + (t >> 4);
        V2s[rg * NCLASS + (t & 15)] = dinv[rg] * (part[t] + part[t + 128]);
    }
}

// ---------------- out[r] = log_softmax(dinv[r]*(V2s[r] + sum w*V2s[c]) + b2) ----------------
// V2s already carries di[c]; weights RAW here.
__global__ __launch_bounds__(256) void agg2_kernel(const int* __restrict__ cnt,
                                                   const int2* __restrict__ ell,
                                                   const float* __restrict__ V2s,
                                                   const float* __restrict__ dinv,
                                                   const float* __restrict__ b2,
                                                   float* __restrict__ out) {
    int t = threadIdx.x;
    int j = t & 15;                   // class
    int r = blockIdx.x * 16 + (t >> 4);
    int n = cnt[r];
    float di = dinv[r];
    float acc = V2s[r * NCLASS + j];  // self term (V2s already dinv-scaled)
    for (int base = 0; base < n; base += 16) {
        int idx = base + j;
        int2 cw = ell[r * ELLS + idx];
        int cc = cw.x & (N_NODES - 1);
        float wl = __int_as_float(cw.y);
        wl = (idx < n) ? wl : 0.0f;
        #pragma unroll
        for (int u = 0; u < 16; ++u) {
            int c = __shfl(cc, u, 16);
            float w = __shfl(wl, u, 16);
            acc += w * V2s[c * NCLASS + j];
        }
    }
    float v = di * acc + b2[j];
    // log_softmax across the 16 lanes of this row-group
    float mx = v;
    #pragma unroll
    for (int off = 1; off < 16; off <<= 1) mx = fmaxf(mx, __shfl_xor(mx, off));
    float ex = expf(v - mx);
    float ssum = ex;
    #pragma unroll
    for (int off = 1; off < 16; off <<= 1) ssum += __shfl_xor(ssum, off);
    out[r * NCLASS + j] = v - mx - logf(ssum);
}

extern "C" void kernel_launch(void* const* d_in, const int* in_sizes, int n_in,
                              void* d_out, int out_size, void* d_ws, size_t ws_size,
                              hipStream_t stream) {
    const float* x  = (const float*)d_in[0];
    const int*   ei = (const int*)d_in[1];      // [2, E] flat: row = ei[e], col = ei[E+e]
    const float* ew = (const float*)d_in[2];
    const float* W1 = (const float*)d_in[3];
    const float* b1 = (const float*)d_in[4];
    const float* W2 = (const float*)d_in[5];
    const float* b2 = (const float*)d_in[6];
    float* out = (float*)d_out;

    const int n = N_NODES;

    char* ws = (char*)d_ws;
    int*   cnt  = (int*)  (ws);                  // [0, 32K)
    float* dinv = (float*)(ws + 32768);          // [32K, 64K)
    int2*  ell  = (int2*) (ws + 65536);          // [64K, 64K+6M): 8192*96*8 B
    float* V2s  = (float*)(ws + 8388608);        // [8M, 8.5M)
    uint4* xs   = (uint4*)(ws + 16777216);       // [16M, 18M): bf16 dinv-scaled x

    zero_kernel<<<32, 256, 0, stream>>>(cnt);

    histscatter_kernel<<<N_EDGES / 256, 256, 0, stream>>>(ei, ew, cnt, ell);
    dinvcvt_kernel<<<n / 16, 256, 0, stream>>>(cnt, ell, x, dinv, xs);

    layer12_kernel<<<n / 8, 256, 0, stream>>>(cnt, ell, (const uint2*)xs,
                                              dinv, W1, b1, W2, V2s);
    agg2_kernel<<<n / 16, 256, 0, stream>>>(cnt, ell, V2s, dinv, b2, out);
}